// Round 3
// baseline (9081.015 us; speedup 1.0000x reference)
//
#include <hip/hip_runtime.h>

namespace {

constexpr int kH  = 768;
constexpr int kW  = 10;
constexpr int kL  = 10;
constexpr int kB  = 512;
constexpr int kG  = 4 * kH;      // 3072
constexpr int kTB = kW * kB;     // 5120

// ---------------- transpose (B,W,H) -> (W,B,H) ----------------
__global__ __launch_bounds__(256) void transpose_bw(const float* __restrict__ src,
                                                    float* __restrict__ dst) {
  int idx = blockIdx.x * 256 + threadIdx.x;       // float4 index
  int h4   = idx % (kH / 4);
  int rest = idx / (kH / 4);
  int b = rest % kB;
  int t = rest / kB;
  const float4* s = reinterpret_cast<const float4*>(src);
  float4* d = reinterpret_cast<float4*>(dst);
  d[((size_t)t * kB + b) * (kH / 4) + h4] = s[((size_t)b * kW + t) * (kH / 4) + h4];
}

// ---------------- pack (W,B,H) -> (B, W*H) ----------------
__global__ __launch_bounds__(256) void pack_xx(const float* __restrict__ src,
                                               float* __restrict__ dst) {
  int idx = blockIdx.x * 256 + threadIdx.x;       // float4 index
  int h4   = idx % (kH / 4);
  int rest = idx / (kH / 4);
  int w = rest % kW;
  int b = rest / kW;
  const float4* s = reinterpret_cast<const float4*>(src);
  float4* d = reinterpret_cast<float4*>(dst);
  d[((size_t)b * kW + w) * (kH / 4) + h4] = s[((size_t)w * kB + b) * (kH / 4) + h4];
}

// ------- GEMM: C[M,N] = A[M,K] @ Wm[N,K]^T (+bias1 +bias2 +Cinit) -------
// All of M%BM==0, N%BN==0, K%BK==0 hold for every call site (no bounds checks).
template <int BM, int BN, int BK, int TM, int TN>
__global__ __launch_bounds__(256) void gemm_awt(
    const float* __restrict__ A, const float* __restrict__ Wm,
    const float* __restrict__ bias1, const float* __restrict__ bias2,
    const float* __restrict__ Cinit, float* __restrict__ C,
    int M, int N, int K) {
  static_assert((BM / TM) * (BN / TN) == 256, "block must be 256 threads");
  __shared__ float As[BK][BM];   // k-major (transposed) so inner reads are float4
  __shared__ float Ws[BK][BN];
  const int tid = threadIdx.x;
  constexpr int NTX = BN / TN;
  const int tx = tid % NTX;
  const int ty = tid / NTX;
  const int bm = blockIdx.y * BM;
  const int bn = blockIdx.x * BN;

  float acc[TM][TN];
#pragma unroll
  for (int i = 0; i < TM; ++i)
#pragma unroll
    for (int j = 0; j < TN; ++j) acc[i][j] = 0.f;

  constexpr int ITA = (BM * BK / 4) / 256;
  constexpr int ITW = (BN * BK / 4) / 256;

  for (int k0 = 0; k0 < K; k0 += BK) {
#pragma unroll
    for (int it = 0; it < ITA; ++it) {
      int e = it * 256 + tid;
      int row = e / (BK / 4);
      int col = (e % (BK / 4)) * 4;
      float4 v = *reinterpret_cast<const float4*>(&A[(size_t)(bm + row) * K + k0 + col]);
      As[col + 0][row] = v.x;
      As[col + 1][row] = v.y;
      As[col + 2][row] = v.z;
      As[col + 3][row] = v.w;
    }
#pragma unroll
    for (int it = 0; it < ITW; ++it) {
      int e = it * 256 + tid;
      int row = e / (BK / 4);
      int col = (e % (BK / 4)) * 4;
      float4 v = *reinterpret_cast<const float4*>(&Wm[(size_t)(bn + row) * K + k0 + col]);
      Ws[col + 0][row] = v.x;
      Ws[col + 1][row] = v.y;
      Ws[col + 2][row] = v.z;
      Ws[col + 3][row] = v.w;
    }
    __syncthreads();
#pragma unroll
    for (int kk = 0; kk < BK; ++kk) {
      float a[TM], w[TN];
#pragma unroll
      for (int i = 0; i < TM; i += 4)
        *reinterpret_cast<float4*>(&a[i]) =
            *reinterpret_cast<const float4*>(&As[kk][ty * TM + i]);
#pragma unroll
      for (int j = 0; j < TN; j += 4)
        *reinterpret_cast<float4*>(&w[j]) =
            *reinterpret_cast<const float4*>(&Ws[kk][tx * TN + j]);
#pragma unroll
      for (int i = 0; i < TM; ++i)
#pragma unroll
        for (int j = 0; j < TN; ++j)
          acc[i][j] = fmaf(a[i], w[j], acc[i][j]);
    }
    __syncthreads();
  }

#pragma unroll
  for (int i = 0; i < TM; ++i) {
    const int row = bm + ty * TM + i;
    const size_t off = (size_t)row * N + bn + tx * TN;
#pragma unroll
    for (int j = 0; j < TN; ++j) {
      float v = acc[i][j];
      if (bias1) v += bias1[bn + tx * TN + j];
      if (bias2) v += bias2[bn + tx * TN + j];
      if (Cinit) v += Cinit[off + j];
      C[off + j] = v;
    }
  }
}

// ---------------- LSTM pointwise gates ----------------
__global__ __launch_bounds__(256) void lstm_pointwise(
    const float* __restrict__ g, float* __restrict__ c,
    float* __restrict__ h_out, int first) {
  int idx = blockIdx.x * 256 + threadIdx.x;       // over B*H
  int b = idx / kH;
  int j = idx % kH;
  const float* gb = g + (size_t)b * kG;
  float gi = gb[j];
  float gf = gb[kH + j];
  float gg = gb[2 * kH + j];
  float go = gb[3 * kH + j];
  float i_ = 1.f / (1.f + __expf(-gi));
  float f_ = 1.f / (1.f + __expf(-gf));
  float g_ = tanhf(gg);
  float o_ = 1.f / (1.f + __expf(-go));
  float cp = first ? 0.f : c[idx];
  float cn = fmaf(f_, cp, i_ * g_);
  c[idx] = cn;
  h_out[idx] = o_ * tanhf(cn);
}

}  // namespace

extern "C" void kernel_launch(void* const* d_in, const int* in_sizes, int n_in,
                              void* d_out, int out_size, void* d_ws, size_t ws_size,
                              hipStream_t stream) {
  const float* xpos  = (const float*)d_in[0];
  const float* fc0_w = (const float*)d_in[1];
  const float* fc0_b = (const float*)d_in[2];
  const float* w_ih  = (const float*)d_in[3];
  const float* w_hh  = (const float*)d_in[4];
  const float* b_ih  = (const float*)d_in[5];
  const float* b_hh  = (const float*)d_in[6];
  const float* fc1_w = (const float*)d_in[7];
  const float* fc1_b = (const float*)d_in[8];
  float* out = (float*)d_out;

  // workspace layout (floats):
  //   Xt : kTB*kH   (transposed input; reused as packed xx for fc1 — same size)
  //   Y  : kTB*kH   (activations, updated in place per layer)
  //   c  : kB*kH    (cell state)
  //   g  : kB*kG    (per-step gate buffer)
  //   gx : kTB*kG   (per-layer input-GEMM result)
  // total = 25,559,040 floats = 102.2 MB
  float* ws = (float*)d_ws;
  float* Xt = ws;
  float* Y  = Xt + (size_t)kTB * kH;
  float* c  = Y + (size_t)kTB * kH;
  float* g  = c + (size_t)kB * kH;
  float* gx = g + (size_t)kB * kG;

  dim3 blk(256);

  transpose_bw<<<kTB * kH / 4 / 256, blk, 0, stream>>>(xpos, Xt);

  // fc0: Y = Xt @ fc0_w^T + fc0_b     (5120 x 768 x 768)
  gemm_awt<64, 64, 16, 4, 4><<<dim3(kH / 64, kTB / 64), blk, 0, stream>>>(
      Xt, fc0_w, fc0_b, nullptr, nullptr, Y, kTB, kH, kH);

  for (int l = 0; l < kL; ++l) {
    const float* wih = w_ih + (size_t)l * kG * kH;
    const float* whh = w_hh + (size_t)l * kG * kH;
    const float* bih = b_ih + (size_t)l * kG;
    const float* bhh = b_hh + (size_t)l * kG;

    // gx = Y @ wih^T + bih + bhh      (5120 x 3072 x 768) — batched over t
    gemm_awt<128, 128, 16, 8, 8><<<dim3(kG / 128, kTB / 128), blk, 0, stream>>>(
        Y, wih, bih, bhh, nullptr, gx, kTB, kG, kH);

    // t = 0: h0 == 0, so gates come straight from gx[0]
    lstm_pointwise<<<kB * kH / 256, blk, 0, stream>>>(gx, c, Y, 1);

    for (int t = 1; t < kW; ++t) {
      // g = gx[t] + h_{t-1} @ whh^T   (512 x 3072 x 768)
      gemm_awt<64, 64, 16, 4, 4><<<dim3(kG / 64, kB / 64), blk, 0, stream>>>(
          Y + (size_t)(t - 1) * kB * kH, whh, nullptr, nullptr,
          gx + (size_t)t * kB * kG, g, kB, kG, kH);
      lstm_pointwise<<<kB * kH / 256, blk, 0, stream>>>(g, c, Y + (size_t)t * kB * kH, 0);
    }
  }

  // fc1: out = xx @ fc1_w^T + fc1_b   (512 x 768 x 7680)
  pack_xx<<<kB * (kW * kH) / 4 / 256, blk, 0, stream>>>(Y, Xt);
  gemm_awt<64, 64, 16, 4, 4><<<dim3(kH / 64, kB / 64), blk, 0, stream>>>(
      Xt, fc1_w, fc1_b, nullptr, nullptr, out, kB, kH, kW * kH);
}

// Round 4
// 3892.497 us; speedup vs baseline: 2.3330x; 2.3330x over previous
//
#include <hip/hip_runtime.h>

namespace {

using u16 = unsigned short;
typedef short s16x8 __attribute__((ext_vector_type(8)));
typedef float f32x4 __attribute__((ext_vector_type(4)));
typedef u16 u16x4 __attribute__((ext_vector_type(4)));

constexpr int kH  = 768;
constexpr int kW  = 10;
constexpr int kL  = 10;
constexpr int kB  = 512;
constexpr int kG  = 3072;      // 4*H
constexpr int kTB = 5120;      // W*B

// ---- bf16 helpers (RNE), bit-level to avoid API differences ----
__device__ __forceinline__ u16 f2bf(float x) {
  unsigned u = __float_as_uint(x);
  unsigned r = (u + 0x7fffu + ((u >> 16) & 1u)) >> 16;
  return (u16)r;
}
__device__ __forceinline__ float bf2f(u16 h) {
  return __uint_as_float(((unsigned)h) << 16);
}

// ---- async global->LDS, 16B per lane, LDS dst is wave-uniform base ----
__device__ __forceinline__ void gl2lds(const void* g, void* l) {
  __builtin_amdgcn_global_load_lds(
      (const __attribute__((address_space(1))) void*)g,
      (__attribute__((address_space(3))) void*)l, 16, 0, 0);
}

__device__ __forceinline__ f32x4 mfma16(s16x8 a, s16x8 b, f32x4 c) {
  return __builtin_amdgcn_mfma_f32_16x16x32_bf16(a, b, c, 0, 0, 0);
}

__device__ __forceinline__ float sigm(float x) { return 1.f / (1.f + __expf(-x)); }

// ---------------- fp32 -> bf16 hi/lo split (4 elems/thread) ----------------
__global__ __launch_bounds__(256) void split4(const float* __restrict__ in,
                                              u16* __restrict__ hi,
                                              u16* __restrict__ lo) {
  int idx = blockIdx.x * 256 + threadIdx.x;
  float4 v = reinterpret_cast<const float4*>(in)[idx];
  u16x4 h, l;
  h[0] = f2bf(v.x); l[0] = f2bf(v.x - bf2f(h[0]));
  h[1] = f2bf(v.y); l[1] = f2bf(v.y - bf2f(h[1]));
  h[2] = f2bf(v.z); l[2] = f2bf(v.z - bf2f(h[2]));
  h[3] = f2bf(v.w); l[3] = f2bf(v.w - bf2f(h[3]));
  reinterpret_cast<u16x4*>(hi)[idx] = h;
  reinterpret_cast<u16x4*>(lo)[idx] = l;
}

// ---------------- transpose (B,W,H)->(W,B,H) + split ----------------
__global__ __launch_bounds__(256) void transpose_split(const float* __restrict__ src,
                                                       u16* __restrict__ hi,
                                                       u16* __restrict__ lo) {
  int idx = blockIdx.x * 256 + threadIdx.x;   // float4 units, 5120*192 total
  int h4 = idx % 192;
  int rest = idx / 192;
  int b = rest % kB;
  int t = rest / kB;
  float4 v = reinterpret_cast<const float4*>(src)[((size_t)b * kW + t) * 192 + h4];
  size_t o = ((size_t)t * kB + b) * 192 + h4;
  u16x4 h, l;
  h[0] = f2bf(v.x); l[0] = f2bf(v.x - bf2f(h[0]));
  h[1] = f2bf(v.y); l[1] = f2bf(v.y - bf2f(h[1]));
  h[2] = f2bf(v.z); l[2] = f2bf(v.z - bf2f(h[2]));
  h[3] = f2bf(v.w); l[3] = f2bf(v.w - bf2f(h[3]));
  reinterpret_cast<u16x4*>(hi)[o] = h;
  reinterpret_cast<u16x4*>(lo)[o] = l;
}

// ---------------- pack (W,B,H)->(B,W*H), bf16 pairs, 8 elems/thread ----------------
__global__ __launch_bounds__(256) void pack_sp(const u16* __restrict__ Yhi,
                                               const u16* __restrict__ Ylo,
                                               u16* __restrict__ Xhi,
                                               u16* __restrict__ Xlo) {
  int idx = blockIdx.x * 256 + threadIdx.x;   // uint4 units (8 u16), 512*7680/8
  int h8 = idx % 96;
  int rest = idx / 96;
  int w = rest % kW;
  int b = rest / kW;
  size_t s = ((size_t)w * kB + b) * 96 + h8;
  size_t d = ((size_t)b * kW + w) * 96 + h8;
  reinterpret_cast<uint4*>(Xhi)[d] = reinterpret_cast<const uint4*>(Yhi)[s];
  reinterpret_cast<uint4*>(Xlo)[d] = reinterpret_cast<const uint4*>(Ylo)[s];
}

// ======== bf16x3 GEMM: C[M,N] = A[M,K] @ W[N,K]^T, MFMA 16x16x32 ========
// BN=128, BK=32 fixed; 4 waves; wave w owns rows [w*BM/4, w*BM/4+BM/4).
// EPI: 0 = fp32 out + bias1; 1 = split hi/lo out + bias1; 2 = fp32 out + bias1 + bias2
template <int BM, int EPI>
__global__ __launch_bounds__(256) void gemm_bf3(
    const u16* __restrict__ Ahi, const u16* __restrict__ Alo,
    const u16* __restrict__ Bhi, const u16* __restrict__ Blo,
    const float* __restrict__ bias1, const float* __restrict__ bias2,
    float* __restrict__ Cf, u16* __restrict__ Chi, u16* __restrict__ Clo,
    int M, int N, int K) {
  constexpr int MR = BM / 64;      // m-fragment repeats per wave
  constexpr int WR = BM / 4;       // rows per wave
  __shared__ u16 sAh[BM * 32], sAl[BM * 32], sBh[128 * 32], sBl[128 * 32];
  const int tid = threadIdx.x;
  const int wid = tid >> 6;
  const int lane = tid & 63;
  const int bm = blockIdx.y * BM;
  const int bn = blockIdx.x * 128;

  f32x4 acc[MR][8];
#pragma unroll
  for (int m = 0; m < MR; ++m)
#pragma unroll
    for (int n = 0; n < 8; ++n) acc[m][n] = {0.f, 0.f, 0.f, 0.f};

  const int ko = (lane >> 4) * 8;          // k-chunk for fragment reads
  const int cl = lane & 15;

  for (int k0 = 0; k0 < K; k0 += 32) {
    // stage A (BM x 32) hi+lo
#pragma unroll
    for (int c = 0; c < MR; ++c) {
      int g16 = (wid * MR + c) * 16;                       // 16-row group
      size_t goff = (size_t)(bm + g16 + (lane >> 2)) * K + k0 + (lane & 3) * 8;
      gl2lds(Ahi + goff, &sAh[g16 * 32]);
      gl2lds(Alo + goff, &sAl[g16 * 32]);
    }
    // stage B (128 x 32) hi+lo
#pragma unroll
    for (int c = 0; c < 2; ++c) {
      int g16 = (wid * 2 + c) * 16;
      size_t goff = (size_t)(bn + g16 + (lane >> 2)) * K + k0 + (lane & 3) * 8;
      gl2lds(Bhi + goff, &sBh[g16 * 32]);
      gl2lds(Blo + goff, &sBl[g16 * 32]);
    }
    __syncthreads();

    s16x8 ah[MR], al[MR];
#pragma unroll
    for (int m = 0; m < MR; ++m) {
      int row = wid * WR + m * 16 + cl;
      ah[m] = *reinterpret_cast<const s16x8*>(&sAh[row * 32 + ko]);
      al[m] = *reinterpret_cast<const s16x8*>(&sAl[row * 32 + ko]);
    }
#pragma unroll
    for (int n = 0; n < 8; ++n) {
      int row = n * 16 + cl;
      s16x8 bh = *reinterpret_cast<const s16x8*>(&sBh[row * 32 + ko]);
      s16x8 bl = *reinterpret_cast<const s16x8*>(&sBl[row * 32 + ko]);
#pragma unroll
      for (int m = 0; m < MR; ++m) acc[m][n] = mfma16(ah[m], bh, acc[m][n]);
#pragma unroll
      for (int m = 0; m < MR; ++m) acc[m][n] = mfma16(ah[m], bl, acc[m][n]);
#pragma unroll
      for (int m = 0; m < MR; ++m) acc[m][n] = mfma16(al[m], bh, acc[m][n]);
    }
    __syncthreads();
  }

  const int rq = (lane >> 4) * 4;
#pragma unroll
  for (int m = 0; m < MR; ++m) {
#pragma unroll
    for (int n = 0; n < 8; ++n) {
      int col = bn + n * 16 + cl;
      float badd = bias1 ? bias1[col] : 0.f;
      if (EPI == 2) badd += bias2[col];
#pragma unroll
      for (int q = 0; q < 4; ++q) {
        int row = bm + wid * WR + m * 16 + rq + q;
        float v = acc[m][n][q] + badd;
        size_t off = (size_t)row * N + col;
        if (EPI == 1) {
          u16 h = f2bf(v);
          Chi[off] = h;
          Clo[off] = f2bf(v - bf2f(h));
        } else {
          Cf[off] = v;
        }
      }
    }
  }
}

// ======== fused recurrent step: g = h_{t-1} @ whh^T + gx[t]; gates; h,c out ====
// BM=64 rows (batch), 32 units * 4 gates = 128 cols. B-tile rows: slab*32+j ->
// W row = slab*768 + u0 + j  (slab = gate). grid = (24, 8).
__global__ __launch_bounds__(256) void lstm_step(
    const u16* __restrict__ Hhi, const u16* __restrict__ Hlo,   // [512][768] at t-1
    const u16* __restrict__ Whi, const u16* __restrict__ Wlo,   // whh split [3072][768]
    const float* __restrict__ gxt,                              // [512][3072] step t
    float* __restrict__ cbuf,                                   // [512][768]
    u16* __restrict__ Ohi, u16* __restrict__ Olo) {             // Y at t
  __shared__ u16 sAh[64 * 32], sAl[64 * 32], sBh[128 * 32], sBl[128 * 32];
  const int tid = threadIdx.x;
  const int wid = tid >> 6;
  const int lane = tid & 63;
  const int u0 = blockIdx.x * 32;
  const int bm = blockIdx.y * 64;

  f32x4 acc[8];
#pragma unroll
  for (int n = 0; n < 8; ++n) acc[n] = {0.f, 0.f, 0.f, 0.f};

  const int ko = (lane >> 4) * 8;
  const int cl = lane & 15;

  for (int k0 = 0; k0 < kH; k0 += 32) {
    {  // A: 64 rows of H
      int g16 = wid * 16;
      size_t goff = (size_t)(bm + g16 + (lane >> 2)) * kH + k0 + (lane & 3) * 8;
      gl2lds(Hhi + goff, &sAh[g16 * 32]);
      gl2lds(Hlo + goff, &sAl[g16 * 32]);
    }
#pragma unroll
    for (int c = 0; c < 2; ++c) {  // B: 128 rows = 4 gate slabs x 32 units
      int g16 = (wid * 2 + c) * 16;
      int slab = g16 >> 5;
      int jb = g16 & 31;
      size_t goff = (size_t)(slab * kH + u0 + jb + (lane >> 2)) * kH + k0 + (lane & 3) * 8;
      gl2lds(Whi + goff, &sBh[g16 * 32]);
      gl2lds(Wlo + goff, &sBl[g16 * 32]);
    }
    __syncthreads();

    int arow = wid * 16 + cl;
    s16x8 ah = *reinterpret_cast<const s16x8*>(&sAh[arow * 32 + ko]);
    s16x8 al = *reinterpret_cast<const s16x8*>(&sAl[arow * 32 + ko]);
#pragma unroll
    for (int n = 0; n < 8; ++n) {
      int row = n * 16 + cl;
      s16x8 bh = *reinterpret_cast<const s16x8*>(&sBh[row * 32 + ko]);
      s16x8 bl = *reinterpret_cast<const s16x8*>(&sBl[row * 32 + ko]);
      acc[n] = mfma16(ah, bh, acc[n]);
      acc[n] = mfma16(ah, bl, acc[n]);
      acc[n] = mfma16(al, bh, acc[n]);
    }
    __syncthreads();
  }

  // epilogue: frag n -> gate n>>1, unit-half n&1. Per lane: all 4 gates of unit u.
  const int rq = (lane >> 4) * 4;
#pragma unroll
  for (int h = 0; h < 2; ++h) {
    int u = u0 + h * 16 + cl;
#pragma unroll
    for (int q = 0; q < 4; ++q) {
      int r = bm + wid * 16 + rq + q;
      size_t gb = (size_t)r * kG;
      float gi = acc[0 + h][q] + gxt[gb + u];
      float gf = acc[2 + h][q] + gxt[gb + kH + u];
      float gg = acc[4 + h][q] + gxt[gb + 2 * kH + u];
      float go = acc[6 + h][q] + gxt[gb + 3 * kH + u];
      float i_ = sigm(gi), f_ = sigm(gf), g_ = tanhf(gg), o_ = sigm(go);
      size_t co = (size_t)r * kH + u;
      float cn = fmaf(f_, cbuf[co], i_ * g_);
      cbuf[co] = cn;
      float hv = o_ * tanhf(cn);
      u16 hh = f2bf(hv);
      Ohi[co] = hh;
      Olo[co] = f2bf(hv - bf2f(hh));
    }
  }
}

// ---------------- t=0 gates (h0 = 0, c0 = 0) ----------------
__global__ __launch_bounds__(256) void lstm_t0(const float* __restrict__ gxt,
                                               float* __restrict__ cbuf,
                                               u16* __restrict__ Ohi,
                                               u16* __restrict__ Olo) {
  int idx = blockIdx.x * 256 + threadIdx.x;   // 512*768
  int b = idx / kH, u = idx % kH;
  size_t base = (size_t)b * kG;
  float gi = gxt[base + u];
  float gg = gxt[base + 2 * kH + u];
  float go = gxt[base + 3 * kH + u];
  float i_ = sigm(gi), g_ = tanhf(gg), o_ = sigm(go);
  float cn = i_ * g_;
  cbuf[idx] = cn;
  float hv = o_ * tanhf(cn);
  u16 hh = f2bf(hv);
  Ohi[idx] = hh;
  Olo[idx] = f2bf(hv - bf2f(hh));
}

}  // namespace

extern "C" void kernel_launch(void* const* d_in, const int* in_sizes, int n_in,
                              void* d_out, int out_size, void* d_ws, size_t ws_size,
                              hipStream_t stream) {
  const float* xpos  = (const float*)d_in[0];
  const float* fc0_w = (const float*)d_in[1];
  const float* fc0_b = (const float*)d_in[2];
  const float* w_ih  = (const float*)d_in[3];
  const float* w_hh  = (const float*)d_in[4];
  const float* b_ih  = (const float*)d_in[5];
  const float* b_hh  = (const float*)d_in[6];
  const float* fc1_w = (const float*)d_in[7];
  const float* fc1_b = (const float*)d_in[8];
  float* out = (float*)d_out;

  // ---- workspace layout (101,449,728 B; round-3 proved >=102 MB available) ----
  // [gx 62.9MB | Y 15.7MB | c 1.6MB | wih_s 9.4MB | whh_s 9.4MB | fc0w_s 2.4MB]
  // gx region aliases: Xt hi/lo (15.7MB, dead after fc0), later xx hi/lo (same)
  // and fc1w_s at +16MB (written after gx dead).
  char* W = (char*)d_ws;
  float* gx    = (float*)W;                               // 5120*3072 f32
  u16* Xthi    = (u16*)W;                                 // 5120*768
  u16* Xtlo    = Xthi + (size_t)kTB * kH;
  u16* fc1whi  = (u16*)(W + 16777216);                    // 768*7680
  u16* fc1wlo  = fc1whi + (size_t)kH * kH * kW;
  u16* Yhi     = (u16*)(W + 62914560);                    // 10*512*768
  u16* Ylo     = Yhi + (size_t)kTB * kH;
  float* cbuf  = (float*)(W + 78643200);                  // 512*768
  u16* wihhi   = (u16*)(W + 80216064);                    // 3072*768
  u16* wihlo   = wihhi + (size_t)kG * kH;
  u16* whhhi   = (u16*)(W + 89653248);
  u16* whhlo   = whhhi + (size_t)kG * kH;
  u16* fc0whi  = (u16*)(W + 99090432);                    // 768*768
  u16* fc0wlo  = fc0whi + (size_t)kH * kH;

  dim3 blk(256);

  // input transpose+split, fc0 weight split
  transpose_split<<<3840, blk, 0, stream>>>(xpos, Xthi, Xtlo);
  split4<<<576, blk, 0, stream>>>(fc0_w, fc0whi, fc0wlo);

  // fc0: Y = Xt @ fc0_w^T + b   (5120 x 768 x 768), split output
  gemm_bf3<128, 1><<<dim3(6, 40), blk, 0, stream>>>(
      Xthi, Xtlo, fc0whi, fc0wlo, fc0_b, nullptr, nullptr, Yhi, Ylo, kTB, kH, kH);

  for (int l = 0; l < kL; ++l) {
    split4<<<2304, blk, 0, stream>>>(w_ih + (size_t)l * kG * kH, wihhi, wihlo);
    split4<<<2304, blk, 0, stream>>>(w_hh + (size_t)l * kG * kH, whhhi, whhlo);

    // gx = Y @ wih^T + b_ih + b_hh   (5120 x 3072 x 768)
    gemm_bf3<128, 2><<<dim3(24, 40), blk, 0, stream>>>(
        Yhi, Ylo, wihhi, wihlo, b_ih + (size_t)l * kG, b_hh + (size_t)l * kG,
        gx, nullptr, nullptr, kTB, kG, kH);

    lstm_t0<<<1536, blk, 0, stream>>>(gx, cbuf, Yhi, Ylo);

    for (int t = 1; t < kW; ++t) {
      lstm_step<<<dim3(24, 8), blk, 0, stream>>>(
          Yhi + (size_t)(t - 1) * kB * kH, Ylo + (size_t)(t - 1) * kB * kH,
          whhhi, whhlo, gx + (size_t)t * kB * kG, cbuf,
          Yhi + (size_t)t * kB * kH, Ylo + (size_t)t * kB * kH);
    }
  }

  // fc1: split weight, pack xx, GEMM (512 x 768 x 7680)
  split4<<<5760, blk, 0, stream>>>(fc1_w, fc1whi, fc1wlo);
  pack_sp<<<1920, blk, 0, stream>>>(Yhi, Ylo, Xthi, Xtlo);
  gemm_bf3<64, 0><<<dim3(6, 8), blk, 0, stream>>>(
      Xthi, Xtlo, fc1whi, fc1wlo, fc1_b, nullptr, out, nullptr, nullptr,
      kB, kH, kW * kH);
}